// Round 1
// baseline (533.576 us; speedup 1.0000x reference)
//
#include <hip/hip_runtime.h>
#include <math.h>

#define NN 50000
#define EE 800000
#define DD 32
#define BSTR 64    // bucket stride (max degree ~45 at Poisson(16); +8 pad fits)
#define NPART 8    // node-range partitions, mapped to XCDs via blockIdx&7
#define CPB 128    // edge chunks per partition (grid = 8*128 = 1024 blocks)

typedef float v2f __attribute__((ext_vector_type(2)));

// ---------------- setup kernels ----------------

__global__ __launch_bounds__(256) void k_zero(float* p, int count){
  int i = blockIdx.x*256 + threadIdx.x;
  if (i < count) p[i] = 0.f;
}

// XCD-partitioned one-pass CSR build (R16-proven: cut write-amp 51->~12 MB).
__global__ __launch_bounds__(256) void k_fillcsr(const int* __restrict__ node_in,
                                                 const int* __restrict__ node_out,
                                                 const float* __restrict__ ew,
                                                 int* __restrict__ cursor,
                                                 int2* __restrict__ csr){
  int part  = blockIdx.x & (NPART-1);
  int group = blockIdx.x >> 3;
  const int per = (EE + CPB - 1) / CPB;   // 6250
  int e0 = group * per;
  int e1 = (e0 + per < EE) ? (e0 + per) : EE;
  unsigned lo = (unsigned)part * 6250u;
  unsigned hi = lo + 6250u;
  for (int e = e0 + threadIdx.x; e < e1; e += 256){
    unsigned o = (unsigned)node_out[e];
    if (o >= lo && o < hi){
      int pos = atomicAdd(&cursor[o], 1);
      int2 v; v.x = node_in[e]; v.y = __float_as_int(ew[e]);
      csr[o*BSTR + pos] = v;
    }
  }
}

// per-node sum(w): 8-lane group per node, coalesced bucket reads, shfl_xor
// reduce; zero the 8-entry pad tail in parallel; block logsum reduce.
__global__ __launch_bounds__(256) void k_sumw(int2* __restrict__ csr,
                                              const int* __restrict__ cursor,
                                              float* __restrict__ deg_w,
                                              float* __restrict__ logsum){
  __shared__ float sf[256];
  int t = threadIdx.x;
  int g = t >> 3, lane = t & 7;
  int n = blockIdx.x*32 + g;
  float s = 0.f;
  if (n < NN){
    int deg = cursor[n];
    int2* row = csr + n*BSTR;
    for (int i = lane; i < deg; i += 8) s += __int_as_float(row[i].y);
    s += __shfl_xor(s, 1);
    s += __shfl_xor(s, 2);
    s += __shfl_xor(s, 4);
    row[deg + lane] = make_int2(0, 0);   // 8 pads, one per lane
    if (lane == 0) deg_w[n] = s;
  }
  sf[t] = (n < NN && lane == 0) ? logf(s + 1.f) : 0.f;
  __syncthreads();
  for (int off = 128; off > 0; off >>= 1){
    if (t < off) sf[t] += sf[t+off];
    __syncthreads();
  }
  if (t == 0) atomicAdd(logsum, sf[0]);
}

// rel_input per layer (6x32), query-part of final MLP (64), and layer-0
// W column-sums over the h-part rows (boundary input is constant per node).
__global__ __launch_bounds__(320) void k_prep(const float* __restrict__ qw,
                                              const float* __restrict__ rel_W,
                                              const float* __restrict__ rel_b,
                                              const float* __restrict__ W1,
                                              const float* __restrict__ b1,
                                              const float* __restrict__ lin_W,
                                              float* __restrict__ rel6,
                                              float* __restrict__ qc,
                                              float* __restrict__ wcol){
  int t = threadIdx.x;
  if (t < 192){
    int l = t >> 5, j = t & 31;
    float s = rel_b[t];
    for (int d = 0; d < 32; ++d) s += qw[d] * rel_W[l*1024 + d*32 + j];
    rel6[t] = s;
  } else if (t < 256){
    int j = t - 192;
    float s = b1[j];
    for (int k = 0; k < 32; ++k) s += qw[k] * W1[(32+k)*64 + j];
    qc[j] = s;
  } else if (t < 288){
    int j = t - 256;
    float s = 0.f;
    for (int k = 0; k < 32; ++k) s += lin_W[k*32 + j];   // layer 0, h-part rows
    wcol[j] = s;
  }
}

// t[n] = dot(h[n], rel_layer5) for msg_score
__global__ __launch_bounds__(256) void k_dot(const float* __restrict__ h,
                                             const float* __restrict__ rel6,
                                             float* __restrict__ tdot){
  int n0 = blockIdx.x*256 + threadIdx.x;
  int n = (n0 < NN) ? n0 : NN-1;
  const float* relr = rel6 + 5*32;
  float s = 0.f;
  #pragma unroll
  for (int d = 0; d < 32; ++d) s += h[n*32 + d] * relr[d];
  if (n0 < NN) tdot[n0] = s;
}

// LDS feature tile: sh[node][feat] with 132-float row stride so phase 2 can
// read each node's 128 feats as 32 x ds_read_b128 (vs 128 strided b32).
#define SROW 132

// ---------------- layer 0 (specialized: boundary input) ----------------
__global__ __launch_bounds__(512, 6) void k_layer0(const float* __restrict__ rel6,
                                               const int* __restrict__ cursor,
                                               const int2* __restrict__ csr,
                                               const int* __restrict__ hidx,
                                               const float* __restrict__ lin_W,
                                               const float* __restrict__ lin_b,
                                               const float* __restrict__ wcol,
                                               const float* __restrict__ deg_w,
                                               const float* __restrict__ logsum,
                                               float* __restrict__ h_next){
  __shared__ __align__(16) float sh[64*SROW];
  int tid = threadIdx.x;
  int base = blockIdx.x * 64;
  int hv0 = *hidx;

  // ---- phase 1: scalar aggregation (csr scan only) ----
  {
    int nl   = tid >> 3;
    int quad = tid & 7;
    float4 r4 = ((const float4*)(rel6))[quad];   // layer 0
    int n0 = base + nl;
    int n = (n0 < NN) ? n0 : NN-1;
    int deg = cursor[n];
    int s0 = n*BSTR, s1 = s0 + deg;
    float S1=0.f, S2=0.f, M=-INFINITY, m=INFINITY;

#define ACCS(C) { \
    float w  = __int_as_float(C.y); \
    float hv = (C.x == hv0) ? 0.f : 100.f; \
    float wm = w * hv; \
    S1 += wm; S2 += wm * hv; \
    M = fmaxf(M, wm); m = fminf(m, wm); }

    int2 cA = csr[s0],   cB = csr[s0+1], cC = csr[s0+2], cD = csr[s0+3];
    int e = s0;
    for (; e + 4 <= s1; e += 4){
      int2 nA = csr[e+4], nB = csr[e+5], nC = csr[e+6], nD = csr[e+7];
      ACCS(cA) ACCS(cB) ACCS(cC) ACCS(cD)
      cA = nA; cB = nB; cC = nC; cD = nD;
    }
    if (e < s1){
      ACCS(cA)
      if (e + 1 < s1){
        ACCS(cB)
        if (e + 2 < s1) ACCS(cC)
      }
    }
#undef ACCS

    float bnd = (n == hv0) ? 0.f : 100.f;
    float cntf = (float)(deg + 1);
#define FIN(cc, rc) { \
    float mxv, mnv; \
    if (deg > 0){ \
      float em = (rc >= 0.f) ? rc*M : rc*m; \
      float en = (rc >= 0.f) ? rc*m : rc*M; \
      mxv = fmaxf(em, bnd); mnv = fminf(en, bnd); \
    } else { mxv = bnd; mnv = bnd; } \
    float meanv = (rc*S1 + bnd) / cntf; \
    float sq    = (rc*rc*S2 + bnd*bnd) / cntf; \
    float sdv   = sqrtf(fmaxf(sq - meanv*meanv, 1e-6f)); \
    int d = quad*4 + cc; \
    float4 o; o.x = meanv; o.y = mxv; o.z = mnv; o.w = sdv; \
    *(float4*)(sh + nl*SROW + d*4) = o; }
    FIN(0, r4.x) FIN(1, r4.y) FIN(2, r4.z) FIN(3, r4.w)
#undef FIN
  }
  __syncthreads();

  // ---- phase 2: linear; x-part = bnd * wcol; 3-sum hoist of sc/iv ----
  {
    const float* Wl = lin_W;   // layer 0
    int lane = tid & 63;
    int j0 = __builtin_amdgcn_readfirstlane((tid >> 6) * 4);
    int n0 = base + lane;
    int n = (n0 < NN) ? n0 : NN-1;
    float mean = *logsum / (float)NN;
    float sc = logf(deg_w[n] + 1.f) / mean;
    float iv = 1.f / fmaxf(sc, 0.01f);
    float bndn = (n == hv0) ? 0.f : 100.f;
    v2f a01p={0,0}, a23p={0,0}, a01s={0,0}, a23s={0,0}, a01i={0,0}, a23i={0,0};

#define CSTAT(dd, cc, fv) { \
    const v2f* w2 = (const v2f*)(Wl + (32 + (dd)*12 + (cc)*3)*32 + j0); \
    v2f fvv; fvv[0]=(fv); fvv[1]=(fv); \
    a01p += fvv*w2[0];  a23p += fvv*w2[1]; \
    a01s += fvv*w2[16]; a23s += fvv*w2[17]; \
    a01i += fvv*w2[32]; a23i += fvv*w2[33]; }

    const float4* frow = (const float4*)(sh + lane*SROW);
    for (int d = 0; d < 32; d += 4){
      float4 fa = frow[d], fb = frow[d+1], fc = frow[d+2], fd = frow[d+3];
      CSTAT(d+0,0,fa.x) CSTAT(d+0,1,fa.y) CSTAT(d+0,2,fa.z) CSTAT(d+0,3,fa.w)
      CSTAT(d+1,0,fb.x) CSTAT(d+1,1,fb.y) CSTAT(d+1,2,fb.z) CSTAT(d+1,3,fb.w)
      CSTAT(d+2,0,fc.x) CSTAT(d+2,1,fc.y) CSTAT(d+2,2,fc.z) CSTAT(d+2,3,fc.w)
      CSTAT(d+3,0,fd.x) CSTAT(d+3,1,fd.y) CSTAT(d+3,2,fd.z) CSTAT(d+3,3,fd.w)
    }
    v2f sc2; sc2[0]=sc; sc2[1]=sc;
    v2f iv2; iv2[0]=iv; iv2[1]=iv;
    v2f a01 = a01p + sc2*a01s + iv2*a01i;
    v2f a23 = a23p + sc2*a23s + iv2*a23i;
    a01[0] += lin_b[j0+0] + bndn*wcol[j0+0];
    a01[1] += lin_b[j0+1] + bndn*wcol[j0+1];
    a23[0] += lin_b[j0+2] + bndn*wcol[j0+2];
    a23[1] += lin_b[j0+3] + bndn*wcol[j0+3];

    if (n0 < NN){
      float vs[4] = { a01[0], a01[1], a23[0], a23[1] };
      #pragma unroll
      for (int j = 0; j < 4; ++j)
        h_next[n0*32 + j0 + j] = fmaxf(vs[j], 0.f);
    }
  }
}

// ---------------- fused per-layer kernel (layers 1..5) ----------------
// R18-proven structure + this round: phase 1 software-pipelines the h-row
// gathers one unroll-group (4 edges) deep -- gathers for e+4..e+7 are issued
// BEFORE consuming e..e+3, so the L2/LLC gather latency is covered by a full
// ACC body instead of ~6 instructions. Phase 2 reads the (transposed) LDS
// feature tile as 32 x ds_read_b128 batched 4/step (one lgkmcnt drain per
// 96 FMAs instead of per 6). PRED (l=5): predecessor tracking in phase 1,
// final MLP fused in the epilogue.
template<bool PRED>
__global__ __launch_bounds__(512, 6) void k_layer(const float* __restrict__ h,
                                               const float* __restrict__ rel6,
                                               const int* __restrict__ cursor,
                                               const int2* __restrict__ csr,
                                               const int* __restrict__ hidx,
                                               const float* __restrict__ tdot,
                                               const float* __restrict__ lin_W,
                                               const float* __restrict__ lin_b,
                                               const float* __restrict__ deg_w,
                                               const float* __restrict__ logsum,
                                               float* __restrict__ h_next,
                                               float* __restrict__ pred_out,
                                               const float* __restrict__ qc,
                                               const float* __restrict__ W1,
                                               const float* __restrict__ W2,
                                               const float* __restrict__ b2,
                                               float* __restrict__ out_score,
                                               int l){
  __shared__ __align__(16) float sh[64*SROW];
  int tid = threadIdx.x;
  int base = blockIdx.x * 64;
  int hv0 = *hidx;

  // ---- phase 1: aggregation (one 8-lane group per node, pipelined x4) ----
  {
    int nl   = tid >> 3;
    int quad = tid & 7;
    float4 r4 = ((const float4*)(rel6 + l*32))[quad];
    int n0 = base + nl;
    bool valid = n0 < NN;
    int n = valid ? n0 : NN-1;
    int deg = cursor[n];
    int s0 = n*BSTR, s1 = s0 + deg;
    v2f S1xy={0,0}, S1zw={0,0}, S2xy={0,0}, S2zw={0,0};
    float M0=-INFINITY,M1=-INFINITY,M2=-INFINITY,M3=-INFINITY;
    float m0=INFINITY,m1=INFINITY,m2=INFINITY,m3=INFINITY;
    float best=-INFINITY; int bi=NN;

#define GATH(C) (((const float4*)(h + (size_t)(C).x*32))[quad])
#define ACC1(C, A, T) { \
    float w = __int_as_float(C.y); \
    v2f wv; wv[0]=w; wv[1]=w; \
    v2f axy; axy[0]=A.x; axy[1]=A.y; \
    v2f azw; azw[0]=A.z; azw[1]=A.w; \
    v2f pxy = wv*axy, pzw = wv*azw; \
    S1xy += pxy; S1zw += pzw; \
    S2xy += pxy*axy; S2zw += pzw*azw; \
    M0=fmaxf(M0,pxy[0]); M1=fmaxf(M1,pxy[1]); M2=fmaxf(M2,pzw[0]); M3=fmaxf(M3,pzw[1]); \
    m0=fminf(m0,pxy[0]); m1=fminf(m1,pxy[1]); m2=fminf(m2,pzw[0]); m3=fminf(m3,pzw[1]); \
    if (PRED){ \
      float sv = w*T; \
      if (sv > best){ best = sv; bi = C.x; } \
      else if (sv == best && C.x < bi) bi = C.x; \
    } }

    // prologue: indices + gathers for the first 4 edges (pad entries -> h[0],
    // harmless, never consumed past s1)
    int2 cA = csr[s0], cB = csr[s0+1], cC = csr[s0+2], cD = csr[s0+3];
    float4 gA = GATH(cA), gB = GATH(cB), gC = GATH(cC), gD = GATH(cD);
    float tA=0.f, tB=0.f, tC=0.f, tD=0.f;
    if (PRED){ tA = tdot[cA.x]; tB = tdot[cB.x]; tC = tdot[cC.x]; tD = tdot[cD.x]; }
    int e = s0;
    for (; e + 8 <= s1; e += 4){
      int2 nA = csr[e+4], nB = csr[e+5], nC = csr[e+6], nD = csr[e+7];
      float4 hA = GATH(nA), hB = GATH(nB), hC = GATH(nC), hD = GATH(nD);
      float uA=0.f, uB=0.f, uC=0.f, uD=0.f;
      if (PRED){ uA = tdot[nA.x]; uB = tdot[nB.x]; uC = tdot[nC.x]; uD = tdot[nD.x]; }
      ACC1(cA, gA, tA)
      ACC1(cB, gB, tB)
      ACC1(cC, gC, tC)
      ACC1(cD, gD, tD)
      cA = nA; cB = nB; cC = nC; cD = nD;
      gA = hA; gB = hB; gC = hC; gD = hD;
      tA = uA; tB = uB; tC = uC; tD = uD;
    }
    // tail: 0..7 edges left; gA..gD hold e..e+3 (pad-safe loads)
    int rem = s1 - e;
    if (rem > 0){
      ACC1(cA, gA, tA)
      if (rem > 1) ACC1(cB, gB, tB)
      if (rem > 2) ACC1(cC, gC, tC)
      if (rem > 3) ACC1(cD, gD, tD)
      if (rem > 4){
        int2 pA = csr[e+4];
        float4 qA = GATH(pA);
        float vA = 0.f; if (PRED) vA = tdot[pA.x];
        ACC1(pA, qA, vA)
        if (rem > 5){
          int2 pB = csr[e+5];
          float4 qB = GATH(pB);
          float vB = 0.f; if (PRED) vB = tdot[pB.x];
          ACC1(pB, qB, vB)
          if (rem > 6){
            int2 pC = csr[e+6];
            float4 qC = GATH(pC);
            float vC = 0.f; if (PRED) vC = tdot[pC.x];
            ACC1(pC, qC, vC)
          }
        }
      }
    }
#undef ACC1
#undef GATH

    float bnd = (n == hv0) ? 0.f : 100.f;
    float cntf = (float)(deg + 1);
#define FIN(cc, rc, S1c, S2c, Mc, mc) { \
    float mxv, mnv; \
    if (deg > 0){ \
      float em = (rc >= 0.f) ? rc*Mc : rc*mc; \
      float en = (rc >= 0.f) ? rc*mc : rc*Mc; \
      mxv = fmaxf(em, bnd); mnv = fminf(en, bnd); \
    } else { mxv = bnd; mnv = bnd; } \
    float meanv = (rc*S1c + bnd) / cntf; \
    float sq    = (rc*rc*S2c + bnd*bnd) / cntf; \
    float sdv   = sqrtf(fmaxf(sq - meanv*meanv, 1e-6f)); \
    int d = quad*4 + cc; \
    float4 o; o.x = meanv; o.y = mxv; o.z = mnv; o.w = sdv; \
    *(float4*)(sh + nl*SROW + d*4) = o; }
    FIN(0, r4.x, S1xy[0], S2xy[0], M0, m0)
    FIN(1, r4.y, S1xy[1], S2xy[1], M1, m1)
    FIN(2, r4.z, S1zw[0], S2zw[0], M2, m2)
    FIN(3, r4.w, S1zw[1], S2zw[1], M3, m3)
#undef FIN
    if (PRED && valid && quad == 0){
      float ss = (n == hv0) ? 0.f : 3200.f;   // boundary self-loop row sum, w=1
      if (ss > best){ best = ss; bi = n; }
      else if (ss == best && n < bi) bi = n;
      pred_out[n] = (float)bi;
    }
  }
  __syncthreads();

  // ---- phase 2: linear (8 waves, wave w -> j0 = w*4; node = lane) ----
  // 3-sum hoist: acc = P + sc*S + iv*I applied once at the end.
  {
    const float* Wl = lin_W + (size_t)l * 13312;
    int lane = tid & 63;
    int j0 = __builtin_amdgcn_readfirstlane((tid >> 6) * 4);
    int n0 = base + lane;
    int n = (n0 < NN) ? n0 : NN-1;
    float mean = *logsum / (float)NN;
    float sc = logf(deg_w[n] + 1.f) / mean;
    float iv = 1.f / fmaxf(sc, 0.01f);
    const float4* hr = (const float4*)(h + (size_t)n*32);
    float4 x0=hr[0],x1=hr[1],x2=hr[2],x3=hr[3],x4=hr[4],x5=hr[5],x6=hr[6],x7=hr[7];
    v2f a01p={0,0}, a23p={0,0}, a01s={0,0}, a23s={0,0}, a01i={0,0}, a23i={0,0};

#define KONE(XV, K) { \
    v2f xv2; xv2[0] = XV; xv2[1] = XV; \
    const v2f* wr2 = (const v2f*)(Wl + (K)*32 + j0); \
    a01p += xv2 * wr2[0]; \
    a23p += xv2 * wr2[1]; }
#define KQ(X, KB) KONE(X.x, KB+0) KONE(X.y, KB+1) KONE(X.z, KB+2) KONE(X.w, KB+3)
    KQ(x0, 0) KQ(x1, 4) KQ(x2, 8) KQ(x3, 12)
    KQ(x4, 16) KQ(x5, 20) KQ(x6, 24) KQ(x7, 28)
#undef KQ
#undef KONE

    const float4* frow = (const float4*)(sh + lane*SROW);
    for (int d = 0; d < 32; d += 4){
      float4 fa = frow[d], fb = frow[d+1], fc = frow[d+2], fd = frow[d+3];
      CSTAT(d+0,0,fa.x) CSTAT(d+0,1,fa.y) CSTAT(d+0,2,fa.z) CSTAT(d+0,3,fa.w)
      CSTAT(d+1,0,fb.x) CSTAT(d+1,1,fb.y) CSTAT(d+1,2,fb.z) CSTAT(d+1,3,fb.w)
      CSTAT(d+2,0,fc.x) CSTAT(d+2,1,fc.y) CSTAT(d+2,2,fc.z) CSTAT(d+2,3,fc.w)
      CSTAT(d+3,0,fd.x) CSTAT(d+3,1,fd.y) CSTAT(d+3,2,fd.z) CSTAT(d+3,3,fd.w)
    }
    v2f sc2; sc2[0]=sc; sc2[1]=sc;
    v2f iv2; iv2[0]=iv; iv2[1]=iv;
    v2f a01 = a01p + sc2*a01s + iv2*a01i;
    v2f a23 = a23p + sc2*a23s + iv2*a23i;
    a01[0] += lin_b[l*32 + j0 + 0];
    a01[1] += lin_b[l*32 + j0 + 1];
    a23[0] += lin_b[l*32 + j0 + 2];
    a23[1] += lin_b[l*32 + j0 + 3];

    float v0r = fmaxf(a01[0], 0.f), v1r = fmaxf(a01[1], 0.f);
    float v2r = fmaxf(a23[0], 0.f), v3r = fmaxf(a23[1], 0.f);

    if (!PRED){
      if (n0 < NN){
        h_next[n0*32 + j0 + 0] = v0r;
        h_next[n0*32 + j0 + 1] = v1r;
        h_next[n0*32 + j0 + 2] = v2r;
        h_next[n0*32 + j0 + 3] = v3r;
      }
    } else {
      // ---- fused final MLP (l=5): h6 never leaves the block ----
      __syncthreads();                    // all phase-2 sh reads complete
      sh[(j0+0)*65 + lane] = v0r;         // stage h6 rows 0..31 (65-stride)
      sh[(j0+1)*65 + lane] = v1r;
      sh[(j0+2)*65 + lane] = v2r;
      sh[(j0+3)*65 + lane] = v3r;
      __syncthreads();
      int node = tid & 63;
      int grp  = __builtin_amdgcn_readfirstlane(tid >> 6);   // 0..7
      int jm = grp*8;                     // wave-uniform -> W1 s_loads
      v2f b0, b1v, b2v, b3;
      b0[0]=qc[jm+0]; b0[1]=qc[jm+1]; b1v[0]=qc[jm+2]; b1v[1]=qc[jm+3];
      b2v[0]=qc[jm+4]; b2v[1]=qc[jm+5]; b3[0]=qc[jm+6]; b3[1]=qc[jm+7];
      for (int k = 0; k < 32; ++k){
        float xv = sh[k*65 + node];
        const v2f* wr = (const v2f*)(W1 + k*64 + jm);
        v2f xv2; xv2[0]=xv; xv2[1]=xv;
        b0 += xv2*wr[0]; b1v += xv2*wr[1]; b2v += xv2*wr[2]; b3 += xv2*wr[3];
      }
      float part = fmaxf(b0[0],0.f)*W2[jm+0] + fmaxf(b0[1],0.f)*W2[jm+1]
                 + fmaxf(b1v[0],0.f)*W2[jm+2] + fmaxf(b1v[1],0.f)*W2[jm+3]
                 + fmaxf(b2v[0],0.f)*W2[jm+4] + fmaxf(b2v[1],0.f)*W2[jm+5]
                 + fmaxf(b3[0],0.f)*W2[jm+6] + fmaxf(b3[1],0.f)*W2[jm+7];
      sh[2080 + node*9 + grp] = part;     // past the 32 staged rows (2080)
      __syncthreads();
      if (tid < 64){
        float s = b2[0];
        #pragma unroll
        for (int g = 0; g < 8; ++g) s += sh[2080 + tid*9 + g];
        if (base + tid < NN) out_score[base + tid] = s;
      }
    }
  }
}

// ---------------- host launch ----------------
extern "C" void kernel_launch(void* const* d_in, const int* in_sizes, int n_in,
                              void* d_out, int out_size, void* d_ws, size_t ws_size,
                              hipStream_t stream){
  const int*   node_in  = (const int*)d_in[0];
  const int*   node_out = (const int*)d_in[1];
  const float* ew       = (const float*)d_in[2];
  const int*   hidx     = (const int*)d_in[3];
  const float* qw       = (const float*)d_in[4];
  const float* rel_W    = (const float*)d_in[5];
  const float* rel_b    = (const float*)d_in[6];
  const float* lin_W    = (const float*)d_in[7];
  const float* lin_b    = (const float*)d_in[8];
  const float* W1       = (const float*)d_in[9];
  const float* b1       = (const float*)d_in[10];
  const float* W2       = (const float*)d_in[11];
  const float* b2       = (const float*)d_in[12];
  float* out_score = (float*)d_out;
  float* out_pred  = out_score + NN;

  char* w = (char*)d_ws;
  size_t off = 0;
  auto take = [&](size_t bytes)->char*{
    char* p = w + off;
    off = (off + bytes + 255) & ~(size_t)255;
    return p;
  };
  size_t bucket_elems = (size_t)NN * BSTR;            // int2 entries
  int2*  csr      = (int2*)take(bucket_elems*8);
  // contiguous zero block: cursor | deg_w | logsum
  char*  zb       = take((size_t)NN*4 + (size_t)NN*4 + 256);
  int*   cursor   = (int*)zb;
  float* deg_w    = (float*)(cursor + NN);
  float* logsum   = (float*)(deg_w + NN);
  int zc = NN + NN + 64;

  float* rel6      = (float*)take(192*4);
  float* qc        = (float*)take(64*4);
  float* wcol      = (float*)take(32*4);
  float* tdot      = (float*)take((size_t)NN*4);
  float* h_a       = (float*)take((size_t)NN*32*4);
  float* h_b       = (float*)take((size_t)NN*32*4);

  int nb  = (NN + 255) / 256;   // 196
  int nsb = (NN + 31) / 32;     // 1563 (k_sumw: 32 nodes/block)
  int nlb = (NN + 63) / 64;     // 782
  k_zero   <<<(zc+255)/256, 256, 0, stream>>>((float*)zb, zc);
  k_fillcsr<<<NPART*CPB, 256, 0, stream>>>(node_in, node_out, ew, cursor, csr);
  k_sumw   <<<nsb, 256, 0, stream>>>(csr, cursor, deg_w, logsum);
  k_prep   <<<1, 320, 0, stream>>>(qw, rel_W, rel_b, W1, b1, lin_W, rel6, qc, wcol);

  // layer 0 (specialized, no h input)
  k_layer0<<<nlb, 512, 0, stream>>>(rel6, cursor, csr, hidx, lin_W, lin_b,
                                    wcol, deg_w, logsum, h_a);

  float* hc = h_a;
  float* hn = h_b;
  for (int l = 1; l < 6; ++l){
    if (l == 5){
      k_dot<<<nb, 256, 0, stream>>>(hc, rel6, tdot);
      k_layer<true><<<nlb, 512, 0, stream>>>(hc, rel6, cursor, csr, hidx, tdot,
                                             lin_W, lin_b, deg_w, logsum,
                                             hn, out_pred,
                                             qc, W1, W2, b2, out_score, l);
    } else {
      k_layer<false><<<nlb, 512, 0, stream>>>(hc, rel6, cursor, csr, hidx, tdot,
                                              lin_W, lin_b, deg_w, logsum,
                                              hn, out_pred,
                                              qc, W1, W2, b2, out_score, l);
    }
    float* t1 = hc; hc = hn; hn = t1;
  }
}